// Round 5
// baseline (427.162 us; speedup 1.0000x reference)
//
#include <hip/hip_runtime.h>
#include <math.h>

#define B_ 32
#define C_ 256
#define N_ 4096
#define HID_ 128
#define OC3_ 384
#define HEADS_ 4
#define DH_ 32
#define LNM_ (C_*N_)
#define CTXP_ 4  // context partial slabs (blocks per bh)

typedef unsigned short u16;
typedef __attribute__((ext_vector_type(8))) short short8;
typedef __attribute__((ext_vector_type(4))) float f32x4;

__device__ inline u16 f2b(float f) {
  union { float f; unsigned int u; } c; c.f = f;
  unsigned int u = c.u;
  return (u16)((u + 0x7fffu + ((u >> 16) & 1u)) >> 16);  // RNE
}
__device__ inline float b2f(u16 b) {
  union { float f; unsigned int u; } c; c.u = (unsigned int)b << 16; return c.f;
}
// HW packed f32x2 -> bf16x2 (RNE), one VALU op (no builtin on gfx950)
__device__ inline unsigned int cvt_pk(float lo, float hi) {
  unsigned int r;
  asm("v_cvt_pk_bf16_f32 %0, %1, %2" : "=v"(r) : "v"(lo), "v"(hi));
  return r;
}
__device__ inline void load_lds16(const u16* g, u16* l) {
  __builtin_amdgcn_global_load_lds(
      (const __attribute__((address_space(1))) void*)g,
      (__attribute__((address_space(3))) void*)l, 16, 0, 0);
}

// ---------------- bf16 MFMA GEMM:  C[b][m][n] = sum_k A[m][k] * B^T ----------------
// 128x128 tile, BK=32, 4 waves (2x2 of 64x64).
// PIPELINED: LDS double-buffer, ONE __syncthreads per k-step.
//   iter t: { stage tile t+1 -> buf[nxt] (cvt+ds_write from regs, or
//             global_load_lds for the !BFUSED B path); issue reg loads for
//             tile t+2; ds_read+MFMA tile t from buf[cur]; __syncthreads }
//   Safety: buf[nxt]'s previous reads (tile t-1) completed before barrier t-1
//   (consumed by MFMAs pre-barrier); __syncthreads' vmcnt(0)+lgkmcnt(0) drain
//   makes all staged data (incl. global_load_lds) visible across waves.
// A: fp32 [Mtot][KDIM] k-contiguous, cast via cvt_pk during reg-staging.
// B: BFUSED  -> fp32 x [b][KDIM][N_]: reg-stage + cvt_pk + involution layout
//               (logical row r -> physical p=(r>>1)|((r&1)<<6); lane-contiguous
//               16B writes; reads apply same map).
//    !BFUSED -> bf16 [b][N_][KDIM] via global_load_lds, LINEAR layout.
template<int KDIM, bool OUTBF16, bool BFUSED>
__global__ __launch_bounds__(256) void k_gemm_mfma(
    const float* __restrict__ Af, const u16* __restrict__ Ball,
    const float* __restrict__ Xall, void* __restrict__ Call,
    const float* __restrict__ bias, float* __restrict__ bsum, int Mtot) {
  constexpr int NT = KDIM / 32;
  int b = blockIdx.z;
  int m0 = blockIdx.y * 128, n0 = blockIdx.x * 128;
  __shared__ __align__(16) u16 As[2][4096];  // 2 x 8 KiB
  __shared__ __align__(16) u16 Bs[2][4096];
  __shared__ float red[8];
  int tid = threadIdx.x;
  int w = tid >> 6, l = tid & 63, l16 = l & 15, quad = l >> 4;
  int wm = w & 1, wn = w >> 1;
  f32x4 acc[4][4] = {};

  const u16* Bt = BFUSED ? nullptr : (Ball + (size_t)b * N_ * KDIM);
  const float* Xb = BFUSED ? (Xall + (size_t)b * KDIM * N_) : nullptr;

  // ---- staging registers (single set; WAR-safe: cvt consumes before reissue) ----
  int am = tid & 127, akh = tid >> 7;
  const float* gaBase = Af + (size_t)(m0 + am) * KDIM + akh * 16;
  float4 a0, a1, a2, a3;
  int nl = (tid & 63) * 2, cb = tid >> 6;
  float2 e0, e1, e2, e3, e4, e5, e6, e7;

  auto a_load = [&](int k0) {
    const float* ga = gaBase + k0;
    a0 = *(const float4*)(ga + 0);
    a1 = *(const float4*)(ga + 4);
    a2 = *(const float4*)(ga + 8);
    a3 = *(const float4*)(ga + 12);
  };
  auto a_write = [&](int bufi) {
    uint4 q0, q1;
    q0.x = cvt_pk(a0.x, a0.y); q0.y = cvt_pk(a0.z, a0.w);
    q0.z = cvt_pk(a1.x, a1.y); q0.w = cvt_pk(a1.z, a1.w);
    q1.x = cvt_pk(a2.x, a2.y); q1.y = cvt_pk(a2.z, a2.w);
    q1.z = cvt_pk(a3.x, a3.y); q1.w = cvt_pk(a3.z, a3.w);
    *(uint4*)&As[bufi][(size_t)(akh * 2 + 0) * 1024 + am * 8] = q0;
    *(uint4*)&As[bufi][(size_t)(akh * 2 + 1) * 1024 + am * 8] = q1;
  };
  auto b_load = [&](int k0) {  // BFUSED only
    const float* gb = Xb + (size_t)(k0 + cb * 8) * N_ + n0 + nl;
    e0 = *(const float2*)(gb + 0 * (size_t)N_);
    e1 = *(const float2*)(gb + 1 * (size_t)N_);
    e2 = *(const float2*)(gb + 2 * (size_t)N_);
    e3 = *(const float2*)(gb + 3 * (size_t)N_);
    e4 = *(const float2*)(gb + 4 * (size_t)N_);
    e5 = *(const float2*)(gb + 5 * (size_t)N_);
    e6 = *(const float2*)(gb + 6 * (size_t)N_);
    e7 = *(const float2*)(gb + 7 * (size_t)N_);
  };
  auto b_write = [&](int bufi) {  // BFUSED only
    uint4 lo, hi;
    lo.x = cvt_pk(e0.x, e1.x); lo.y = cvt_pk(e2.x, e3.x);
    lo.z = cvt_pk(e4.x, e5.x); lo.w = cvt_pk(e6.x, e7.x);
    hi.x = cvt_pk(e0.y, e1.y); hi.y = cvt_pk(e2.y, e3.y);
    hi.z = cvt_pk(e4.y, e5.y); hi.w = cvt_pk(e6.y, e7.y);
    int prow = nl >> 1;  // lane-contiguous 16B writes
    *(uint4*)&Bs[bufi][(size_t)cb * 1024 + (size_t)prow * 8] = lo;
    *(uint4*)&Bs[bufi][(size_t)cb * 1024 + (size_t)(64 + prow) * 8] = hi;
  };
  auto b_async = [&](int k0, int bufi) {  // !BFUSED only: async global->LDS
    #pragma unroll
    for (int i = 0; i < 2; i++) {
      int chunk = i * 256 + tid;
      int c = chunk >> 7, m = chunk & 127;
      const u16* gb = Bt + (size_t)(n0 + m) * KDIM + k0 + c * 8;
      u16* lb = &Bs[bufi][(size_t)(i * 256 + (tid & ~63)) * 8];
      load_lds16(gb, lb);
    }
  };
  auto compute = [&](int bufi) {
    short8 af[4], bf[4];
    #pragma unroll
    for (int mi = 0; mi < 4; mi++)
      af[mi] = *(const short8*)&As[bufi][(size_t)(quad * 128 + wm * 64 + mi * 16 + l16) * 8];
    #pragma unroll
    for (int nj = 0; nj < 4; nj++) {
      int rr = wn * 64 + nj * 16 + l16;
      int pp;
      if constexpr (BFUSED) pp = (rr >> 1) | ((rr & 1) << 6);
      else pp = rr;
      bf[nj] = *(const short8*)&Bs[bufi][(size_t)(quad * 128 + pp) * 8];
    }
    #pragma unroll
    for (int mi = 0; mi < 4; mi++)
      #pragma unroll
      for (int nj = 0; nj < 4; nj++)
        acc[mi][nj] = __builtin_amdgcn_mfma_f32_16x16x32_bf16(af[mi], bf[nj], acc[mi][nj], 0, 0, 0);
  };

  // ---- prologue: tile 0 -> buf0; issue reg loads for tile 1 ----
  a_load(0);
  if constexpr (BFUSED) b_load(0); else b_async(0, 0);
  a_write(0);
  if constexpr (BFUSED) b_write(0);
  a_load(32);
  if constexpr (BFUSED) b_load(32);
  __syncthreads();

  #pragma unroll
  for (int t = 0; t < NT; t++) {
    int cur = t & 1, nxt = cur ^ 1;
    if (t + 1 < NT) {
      a_write(nxt);                            // cvt+write tile t+1 (from regs)
      if constexpr (BFUSED) b_write(nxt);
      else b_async((t + 1) * 32, nxt);         // async tile t+1, drained at barrier
      if (t + 2 < NT) {
        a_load((t + 2) * 32);                  // reissue regs for tile t+2
        if constexpr (BFUSED) b_load((t + 2) * 32);
      }
    }
    compute(cur);
    __syncthreads();
  }

  if constexpr (OUTBF16) {
    u16* Co = (u16*)Call + (size_t)b * Mtot * N_;
    u16* lw = &As[0][w * 1024];  // 16 rows x 64 cols bf16 scratch per wave
    #pragma unroll
    for (int mi = 0; mi < 4; mi++) {
      #pragma unroll
      for (int nj = 0; nj < 4; nj++)
        #pragma unroll
        for (int r = 0; r < 4; r++)
          lw[(quad * 4 + r) * 64 + nj * 16 + l16] = f2b(acc[mi][nj][r]);
      #pragma unroll
      for (int p = 0; p < 2; p++) {
        int chunk = p * 64 + l;           // 128 chunks of 8 bf16
        int row = chunk >> 3, cc = chunk & 7;
        uint4 v = *(const uint4*)&lw[chunk * 8];
        *(uint4*)&Co[(size_t)(m0 + wm * 64 + mi * 16 + row) * N_ + n0 + wn * 64 + cc * 8] = v;
      }
    }
  } else {
    float* Co = (float*)Call + (size_t)b * Mtot * N_;
    float s1 = 0.f, s2 = 0.f;
    #pragma unroll
    for (int mi = 0; mi < 4; mi++)
      #pragma unroll
      for (int r = 0; r < 4; r++) {
        int m = m0 + wm * 64 + mi * 16 + quad * 4 + r;
        float bv = bias[m];
        #pragma unroll
        for (int nj = 0; nj < 4; nj++) {
          int n = n0 + wn * 64 + nj * 16 + l16;
          float v = acc[mi][nj][r] + bv;
          s1 += v; s2 += v * v;
          Co[(size_t)m * N_ + n] = v;
        }
      }
    #pragma unroll
    for (int o = 32; o; o >>= 1) { s1 += __shfl_xor(s1, o); s2 += __shfl_xor(s2, o); }
    if (l == 0) { red[w] = s1; red[4 + w] = s2; }
    __syncthreads();
    if (tid == 0) {
      atomicAdd(&bsum[2 * b],     red[0] + red[1] + red[2] + red[3]);
      atomicAdd(&bsum[2 * b + 1], red[4] + red[5] + red[6] + red[7]);
    }
  }
}

// ---------------- K2a: k-softmax stats over n (+ zero bsum for gemm2) ----------------
__global__ __launch_bounds__(256) void k_kstats(const u16* __restrict__ qkvb,
    float* __restrict__ rmax, float* __restrict__ rinv, float* __restrict__ bsum) {
  int r = blockIdx.x;
  int b = r >> 7, rem = r & 127;
  const u16* row = qkvb + (size_t)b * OC3_ * N_ + (size_t)(HID_ + rem) * N_;
  int tid = threadIdx.x;
  if (r == 0 && tid < 64) bsum[tid] = 0.f;
  float v[16];
  #pragma unroll
  for (int p = 0; p < 2; p++) {
    uint4 u = *(const uint4*)&row[(size_t)(p * 256 + tid) * 8];
    unsigned int uu[4] = {u.x, u.y, u.z, u.w};
    #pragma unroll
    for (int j = 0; j < 4; j++) {
      v[p * 8 + j * 2 + 0] = b2f((u16)(uu[j] & 0xffff));
      v[p * 8 + j * 2 + 1] = b2f((u16)(uu[j] >> 16));
    }
  }
  float m = -1e30f;
  #pragma unroll
  for (int i = 0; i < 16; i++) m = fmaxf(m, v[i]);
  #pragma unroll
  for (int o = 32; o; o >>= 1) m = fmaxf(m, __shfl_xor(m, o));
  __shared__ float sm[4], ss[4];
  int w = tid >> 6;
  if ((tid & 63) == 0) sm[w] = m;
  __syncthreads();
  m = fmaxf(fmaxf(sm[0], sm[1]), fmaxf(sm[2], sm[3]));
  float s = 0.f;
  #pragma unroll
  for (int i = 0; i < 16; i++) s += __expf(v[i] - m);
  #pragma unroll
  for (int o = 32; o; o >>= 1) s += __shfl_xor(s, o);
  if ((tid & 63) == 0) ss[w] = s;
  __syncthreads();
  if (tid == 0) {
    rmax[r] = m;
    rinv[r] = 1.f / (ss[0] + ss[1] + ss[2] + ss[3]);
  }
}

// ---------------- K2b (MFMA): ctx_part[blk][bh][d][e] = sum_n p[d][n]*v[e][n] ----------------
__global__ __launch_bounds__(256) void k_context(const u16* __restrict__ qkvb,
    const float* __restrict__ rmax, const float* __restrict__ rinv,
    float* __restrict__ ctxp) {
  int blk = blockIdx.x, bh = blockIdx.y;
  int b = bh >> 2, hd = bh & 3;
  const u16* kb = qkvb + (size_t)b * OC3_ * N_ + (size_t)(HID_ + hd * DH_) * N_;
  const u16* vb = qkvb + (size_t)b * OC3_ * N_ + (size_t)(2 * HID_ + hd * DH_) * N_;
  __shared__ float redl[4096];  // 4 waves x 32x32 fp32 = 16 KiB
  int tid = threadIdx.x;
  int w = tid >> 6, l = tid & 63, l16 = l & 15, quad = l >> 4;
  float rm[2], ri[2];
  #pragma unroll
  for (int mi = 0; mi < 2; mi++) {
    rm[mi] = rmax[bh * 32 + mi * 16 + l16];
    ri[mi] = rinv[bh * 32 + mi * 16 + l16];
  }
  f32x4 acc[2][2] = {};
  int nbase = blk * 1024 + w * 256 + quad * 8;
  #pragma unroll
  for (int kk = 0; kk < 8; kk++) {
    int n0 = nbase + kk * 32;
    short8 af[2], bf[2];
    #pragma unroll
    for (int nj = 0; nj < 2; nj++)
      bf[nj] = *(const short8*)&vb[(size_t)(nj * 16 + l16) * N_ + n0];
    #pragma unroll
    for (int mi = 0; mi < 2; mi++) {
      uint4 u = *(const uint4*)&kb[(size_t)(mi * 16 + l16) * N_ + n0];
      unsigned int uu[4] = {u.x, u.y, u.z, u.w};
      union { unsigned int u[4]; short8 s; } pk;
      #pragma unroll
      for (int j = 0; j < 4; j++) {
        float lo = __expf(b2f((u16)(uu[j] & 0xffff)) - rm[mi]) * ri[mi];
        float hi = __expf(b2f((u16)(uu[j] >> 16))     - rm[mi]) * ri[mi];
        pk.u[j] = cvt_pk(lo, hi);
      }
      af[mi] = pk.s;
    }
    #pragma unroll
    for (int mi = 0; mi < 2; mi++)
      #pragma unroll
      for (int nj = 0; nj < 2; nj++)
        acc[mi][nj] = __builtin_amdgcn_mfma_f32_16x16x32_bf16(af[mi], bf[nj], acc[mi][nj], 0, 0, 0);
  }
  #pragma unroll
  for (int mi = 0; mi < 2; mi++)
    #pragma unroll
    for (int nj = 0; nj < 2; nj++)
      #pragma unroll
      for (int r = 0; r < 4; r++)
        redl[w * 1024 + (mi * 16 + quad * 4 + r) * 32 + nj * 16 + l16] = acc[mi][nj][r];
  __syncthreads();
  float* cp = ctxp + (size_t)blk * 131072 + (size_t)bh * 1024;
  #pragma unroll
  for (int j = 0; j < 4; j++) {
    int idx = j * 256 + tid;
    cp[idx] = redl[idx] + redl[1024 + idx] + redl[2048 + idx] + redl[3072 + idx];
  }
}

// ---------------- K3: q-softmax + hid = ctx^T . q -> hidt[b][n][e] bf16 ----------------
__global__ __launch_bounds__(256) void k_attnout(const u16* __restrict__ qkvb,
    const float* __restrict__ ctxp, u16* __restrict__ hidt) {
  int tile = blockIdx.x, bh = blockIdx.y;
  int b = bh >> 2, hd = bh & 3;
  const u16* qbase = qkvb + (size_t)b * OC3_ * N_ + (size_t)(hd * DH_) * N_;
  __shared__ float cs[32][40];
  __shared__ unsigned int hs[256][16];  // 256 n x 32 bf16 (packed pairs)
  int tid = threadIdx.x;
  for (int idx = tid; idx < 1024; idx += 256) {
    float s = 0.f;
    #pragma unroll
    for (int p = 0; p < CTXP_; p++)
      s += ctxp[(size_t)p * 131072 + (size_t)bh * 1024 + idx];
    int d = idx >> 5, e = idx & 31;
    cs[d][e] = s;
  }
  __syncthreads();
  int n = tile * 256 + tid;
  float q[32];
  float m = -1e30f;
  #pragma unroll
  for (int d = 0; d < 32; d++) { q[d] = b2f(qbase[(size_t)d * N_ + n]); m = fmaxf(m, q[d]); }
  float s = 0.f;
  #pragma unroll
  for (int d = 0; d < 32; d++) { q[d] = __expf(q[d] - m); s += q[d]; }
  float inv = 0.17677669529663687f / s;  // 1/sqrt(32)
  #pragma unroll
  for (int d = 0; d < 32; d++) q[d] *= inv;
  #pragma unroll
  for (int e0 = 0; e0 < 32; e0 += 4) {
    f32x4 a = {};
    #pragma unroll
    for (int d = 0; d < 32; d++) {
      f32x4 c4 = *(const f32x4*)&cs[d][e0];
      a += q[d] * c4;
    }
    hs[tid][e0 / 2 + 0] = cvt_pk(a[0], a[1]);
    hs[tid][e0 / 2 + 1] = cvt_pk(a[2], a[3]);
  }
  __syncthreads();
  #pragma unroll
  for (int it = 0; it < 8; it++) {
    int q2 = it * 256 + tid;          // uint2 chunk: 8 chunks per n-row
    int nl = q2 >> 3, c2 = q2 & 7;
    uint2 v = *(const uint2*)&hs[nl][c2 * 2];
    *(uint2*)&hidt[((size_t)b * N_ + tile * 256 + nl) * HID_ + hd * 32 + c2 * 4] = v;
  }
}

// ---------------- K5: finalize mean/rstd ----------------
__global__ void k_finalize(float* __restrict__ bsum) {
  int b = threadIdx.x;
  if (b < B_) {
    float s1 = bsum[2 * b], s2 = bsum[2 * b + 1];
    float mean = s1 * (1.f / LNM_);
    float var = s2 * (1.f / LNM_) - mean * mean;
    bsum[2 * b] = mean;
    bsum[2 * b + 1] = rsqrtf(var + 1e-5f);
  }
}

// ---------------- K6: normalize + affine in-place ----------------
__global__ __launch_bounds__(256) void k_norm(float* __restrict__ out,
    const float* __restrict__ bsum, const float* __restrict__ gnw,
    const float* __restrict__ gnb) {
  size_t v = (size_t)blockIdx.x * 256 + threadIdx.x;
  int c = (int)((v >> 10) & 255);
  int b = (int)(v >> 18);
  float mean = bsum[2 * b], rstd = bsum[2 * b + 1];
  float w = gnw[c] * rstd;
  float sh = gnb[c] - mean * w;
  float4 x = ((const float4*)out)[v];
  x.x = x.x * w + sh; x.y = x.y * w + sh;
  x.z = x.z * w + sh; x.w = x.w * w + sh;
  ((float4*)out)[v] = x;
}

extern "C" void kernel_launch(void* const* d_in, const int* in_sizes, int n_in,
                              void* d_out, int out_size, void* d_ws, size_t ws_size,
                              hipStream_t stream) {
  const float* x     = (const float*)d_in[0];
  const float* w_qkv = (const float*)d_in[1];
  const float* w_out = (const float*)d_in[2];
  const float* b_out = (const float*)d_in[3];
  const float* gn_w  = (const float*)d_in[4];
  const float* gn_b  = (const float*)d_in[5];
  float* out = (float*)d_out;

  u16* qkvb = (u16*)d_ws;                              // 96 MiB
  u16* hidt = qkvb + (size_t)B_ * OC3_ * N_;           // 32 MiB
  float* ctx  = (float*)(hidt + (size_t)B_ * N_ * HID_);  // 2 MiB (4 partial slabs)
  float* bsum = ctx + CTXP_ * 131072;                  // 64
  float* rmax = bsum + 64;                             // 4096
  float* rinv = rmax + 4096;                           // 4096

  k_gemm_mfma<256, true, true><<<dim3(32, 3, 32), 256, 0, stream>>>(
      w_qkv, nullptr, x, qkvb, nullptr, nullptr, OC3_);
  k_kstats<<<4096, 256, 0, stream>>>(qkvb, rmax, rinv, bsum);
  k_context<<<dim3(CTXP_, 128), 256, 0, stream>>>(qkvb, rmax, rinv, ctx);
  k_attnout<<<dim3(16, 128), 256, 0, stream>>>(qkvb, ctx, hidt);
  k_gemm_mfma<128, false, false><<<dim3(32, 2, 32), 256, 0, stream>>>(
      w_out, hidt, nullptr, out, b_out, bsum, C_);
  k_finalize<<<1, 64, 0, stream>>>(bsum);
  k_norm<<<32768, 256, 0, stream>>>(out, bsum, gn_w, gn_b);
}

// Round 8
// 408.179 us; speedup vs baseline: 1.0465x; 1.0465x over previous
//
#include <hip/hip_runtime.h>
#include <math.h>

#define B_ 32
#define C_ 256
#define N_ 4096
#define HID_ 128
#define OC3_ 384
#define HEADS_ 4
#define DH_ 32
#define LNM_ (C_*N_)
#define CTXP_ 4  // context partial slabs (blocks per bh)

typedef unsigned short u16;
typedef __attribute__((ext_vector_type(8))) short short8;
typedef __attribute__((ext_vector_type(4))) float f32x4;

__device__ inline u16 f2b(float f) {
  union { float f; unsigned int u; } c; c.f = f;
  unsigned int u = c.u;
  return (u16)((u + 0x7fffu + ((u >> 16) & 1u)) >> 16);  // RNE
}
__device__ inline float b2f(u16 b) {
  union { float f; unsigned int u; } c; c.u = (unsigned int)b << 16; return c.f;
}
// HW packed f32x2 -> bf16x2 (RNE), one VALU op (no builtin on gfx950)
__device__ inline unsigned int cvt_pk(float lo, float hi) {
  unsigned int r;
  asm("v_cvt_pk_bf16_f32 %0, %1, %2" : "=v"(r) : "v"(lo), "v"(hi));
  return r;
}
__device__ inline void load_lds16(const u16* g, u16* l) {
  __builtin_amdgcn_global_load_lds(
      (const __attribute__((address_space(1))) void*)g,
      (__attribute__((address_space(3))) void*)l, 16, 0, 0);
}

// ---------------- K-1: cast weights to bf16 (+ zero bsum) ----------------
// Restored: the fp32 A-register-scatter staging (R3-R5) was the gemm regression —
// per-lane rows 1 KB apart = 64 cache lines/instr + load->cvt->ds_write dep chain
// in every k-step. Precast once, stage via global_load_lds (no VGPR round-trip).
__global__ void k_cast_w(const float* __restrict__ wq, const float* __restrict__ wo,
                         u16* __restrict__ wqb, u16* __restrict__ wob,
                         float* __restrict__ bsum) {
  int i = blockIdx.x * 256 + threadIdx.x;
  if (i < OC3_ * C_) wqb[i] = f2b(wq[i]);
  if (i < C_ * HID_) wob[i] = f2b(wo[i]);
  if (i < 64) bsum[i] = 0.f;
}

// ---------------- bf16 MFMA GEMM:  C[b][m][n] = sum_k A[m][k] * B^T ----------------
// 128x128 tile, BK=32, 4 waves (2x2 of 64x64). Single-buffer, 2 barriers/k-step
// (R2-proven structure; explicit dbuf regressed — R5, guide m99/m100).
// A: bf16 [Mtot][KDIM] via global_load_lds (async, no reg dependency).
// B: BFUSED  -> fp32 x [b][KDIM][N_]: reg-stage + cvt_pk + involution layout
//               (logical row r -> physical p=(r>>1)|((r&1)<<6); lane-contiguous
//               16B writes). Reg loads for tile t+1 issued right after barrier-1
//               so HBM/L2 latency hides under compute(t) (T14).
//    !BFUSED -> bf16 [b][N_][KDIM] via global_load_lds, LINEAR layout.
template<int KDIM, bool OUTBF16, bool BFUSED>
__global__ __launch_bounds__(256) void k_gemm_mfma(
    const u16* __restrict__ A, const u16* __restrict__ Ball,
    const float* __restrict__ Xall, void* __restrict__ Call,
    const float* __restrict__ bias, float* __restrict__ bsum, int Mtot) {
  constexpr int NT = KDIM / 32;
  int b = blockIdx.z;
  int m0 = blockIdx.y * 128, n0 = blockIdx.x * 128;
  __shared__ __align__(16) u16 As[4096];  // 4 chunks * 128 rows * 8 bf16 = 8 KiB
  __shared__ __align__(16) u16 Bs[4096];
  __shared__ float red[8];
  int tid = threadIdx.x;
  int w = tid >> 6, l = tid & 63, l16 = l & 15, quad = l >> 4;
  int wm = w & 1, wn = w >> 1;
  f32x4 acc[4][4] = {};

  const u16* Bt = BFUSED ? nullptr : (Ball + (size_t)b * N_ * KDIM);
  const float* Xb = BFUSED ? (Xall + (size_t)b * KDIM * N_) : nullptr;

  int nl = (tid & 63) * 2, cb = tid >> 6;
  float2 e0, e1, e2, e3, e4, e5, e6, e7;

  auto a_async = [&](int k0) {
    #pragma unroll
    for (int i = 0; i < 2; i++) {
      int chunk = i * 256 + tid;
      int c = chunk >> 7, m = chunk & 127;
      const u16* ga = A + (size_t)(m0 + m) * KDIM + k0 + c * 8;
      u16* la = As + (size_t)(i * 256 + (tid & ~63)) * 8;
      load_lds16(ga, la);
    }
  };
  auto b_async = [&](int k0) {  // !BFUSED only
    #pragma unroll
    for (int i = 0; i < 2; i++) {
      int chunk = i * 256 + tid;
      int c = chunk >> 7, m = chunk & 127;
      const u16* gb = Bt + (size_t)(n0 + m) * KDIM + k0 + c * 8;
      u16* lb = Bs + (size_t)(i * 256 + (tid & ~63)) * 8;
      load_lds16(gb, lb);
    }
  };
  auto b_load = [&](int k0) {  // BFUSED only: 512B-coalesced fp32 reads
    const float* gb = Xb + (size_t)(k0 + cb * 8) * N_ + n0 + nl;
    e0 = *(const float2*)(gb + 0 * (size_t)N_);
    e1 = *(const float2*)(gb + 1 * (size_t)N_);
    e2 = *(const float2*)(gb + 2 * (size_t)N_);
    e3 = *(const float2*)(gb + 3 * (size_t)N_);
    e4 = *(const float2*)(gb + 4 * (size_t)N_);
    e5 = *(const float2*)(gb + 5 * (size_t)N_);
    e6 = *(const float2*)(gb + 6 * (size_t)N_);
    e7 = *(const float2*)(gb + 7 * (size_t)N_);
  };
  auto b_write = [&]() {  // BFUSED only: cvt + lane-contiguous 16B LDS writes
    uint4 lo, hi;
    lo.x = cvt_pk(e0.x, e1.x); lo.y = cvt_pk(e2.x, e3.x);
    lo.z = cvt_pk(e4.x, e5.x); lo.w = cvt_pk(e6.x, e7.x);
    hi.x = cvt_pk(e0.y, e1.y); hi.y = cvt_pk(e2.y, e3.y);
    hi.z = cvt_pk(e4.y, e5.y); hi.w = cvt_pk(e6.y, e7.y);
    int prow = nl >> 1;
    *(uint4*)&Bs[(size_t)cb * 1024 + (size_t)prow * 8] = lo;
    *(uint4*)&Bs[(size_t)cb * 1024 + (size_t)(64 + prow) * 8] = hi;
  };
  auto compute = [&]() {
    short8 af[4], bf[4];
    #pragma unroll
    for (int mi = 0; mi < 4; mi++)
      af[mi] = *(const short8*)&As[(size_t)(quad * 128 + wm * 64 + mi * 16 + l16) * 8];
    #pragma unroll
    for (int nj = 0; nj < 4; nj++) {
      int rr = wn * 64 + nj * 16 + l16;
      int pp;
      if constexpr (BFUSED) pp = (rr >> 1) | ((rr & 1) << 6);  // involution
      else pp = rr;
      bf[nj] = *(const short8*)&Bs[(size_t)(quad * 128 + pp) * 8];
    }
    #pragma unroll
    for (int mi = 0; mi < 4; mi++)
      #pragma unroll
      for (int nj = 0; nj < 4; nj++)
        acc[mi][nj] = __builtin_amdgcn_mfma_f32_16x16x32_bf16(af[mi], bf[nj], acc[mi][nj], 0, 0, 0);
  };

  if constexpr (BFUSED) b_load(0);
  #pragma unroll
  for (int t = 0; t < NT; t++) {
    if constexpr (BFUSED) b_write();     // cvt regs(t) -> Bs
    a_async(t * 32);                     // async A -> As (drained at barrier)
    if constexpr (!BFUSED) b_async(t * 32);
    __syncthreads();                     // tile t staged & visible
    if constexpr (BFUSED) {
      if (t + 1 < NT) b_load((t + 1) * 32);  // issue early: hides under compute
    }
    compute();
    __syncthreads();                     // reads done; buffers reusable
  }

  if constexpr (OUTBF16) {
    u16* Co = (u16*)Call + (size_t)b * Mtot * N_;
    u16* lw = As + w * 1024;  // 16 rows x 64 cols bf16 scratch per wave
    #pragma unroll
    for (int mi = 0; mi < 4; mi++) {
      #pragma unroll
      for (int nj = 0; nj < 4; nj++)
        #pragma unroll
        for (int r = 0; r < 4; r++)
          lw[(quad * 4 + r) * 64 + nj * 16 + l16] = f2b(acc[mi][nj][r]);
      #pragma unroll
      for (int p = 0; p < 2; p++) {
        int chunk = p * 64 + l;           // 128 chunks of 8 bf16
        int row = chunk >> 3, cc = chunk & 7;
        uint4 v = *(const uint4*)&lw[chunk * 8];
        *(uint4*)&Co[(size_t)(m0 + wm * 64 + mi * 16 + row) * N_ + n0 + wn * 64 + cc * 8] = v;
      }
    }
  } else {
    float* Co = (float*)Call + (size_t)b * Mtot * N_;
    float s1 = 0.f, s2 = 0.f;
    #pragma unroll
    for (int mi = 0; mi < 4; mi++)
      #pragma unroll
      for (int r = 0; r < 4; r++) {
        int m = m0 + wm * 64 + mi * 16 + quad * 4 + r;
        float bv = bias[m];
        #pragma unroll
        for (int nj = 0; nj < 4; nj++) {
          int n = n0 + wn * 64 + nj * 16 + l16;
          float v = acc[mi][nj][r] + bv;
          s1 += v; s2 += v * v;
          Co[(size_t)m * N_ + n] = v;
        }
      }
    #pragma unroll
    for (int o = 32; o; o >>= 1) { s1 += __shfl_xor(s1, o); s2 += __shfl_xor(s2, o); }
    if (l == 0) { red[w] = s1; red[4 + w] = s2; }
    __syncthreads();
    if (tid == 0) {
      atomicAdd(&bsum[2 * b],     red[0] + red[1] + red[2] + red[3]);
      atomicAdd(&bsum[2 * b + 1], red[4] + red[5] + red[6] + red[7]);
    }
  }
}

// ---------------- K2a: k-softmax stats over n ----------------
__global__ __launch_bounds__(256) void k_kstats(const u16* __restrict__ qkvb,
    float* __restrict__ rmax, float* __restrict__ rinv) {
  int r = blockIdx.x;
  int b = r >> 7, rem = r & 127;
  const u16* row = qkvb + (size_t)b * OC3_ * N_ + (size_t)(HID_ + rem) * N_;
  int tid = threadIdx.x;
  float v[16];
  #pragma unroll
  for (int p = 0; p < 2; p++) {
    uint4 u = *(const uint4*)&row[(size_t)(p * 256 + tid) * 8];
    unsigned int uu[4] = {u.x, u.y, u.z, u.w};
    #pragma unroll
    for (int j = 0; j < 4; j++) {
      v[p * 8 + j * 2 + 0] = b2f((u16)(uu[j] & 0xffff));
      v[p * 8 + j * 2 + 1] = b2f((u16)(uu[j] >> 16));
    }
  }
  float m = -1e30f;
  #pragma unroll
  for (int i = 0; i < 16; i++) m = fmaxf(m, v[i]);
  #pragma unroll
  for (int o = 32; o; o >>= 1) m = fmaxf(m, __shfl_xor(m, o));
  __shared__ float sm[4], ss[4];
  int w = tid >> 6;
  if ((tid & 63) == 0) sm[w] = m;
  __syncthreads();
  m = fmaxf(fmaxf(sm[0], sm[1]), fmaxf(sm[2], sm[3]));
  float s = 0.f;
  #pragma unroll
  for (int i = 0; i < 16; i++) s += __expf(v[i] - m);
  #pragma unroll
  for (int o = 32; o; o >>= 1) s += __shfl_xor(s, o);
  if ((tid & 63) == 0) ss[w] = s;
  __syncthreads();
  if (tid == 0) {
    rmax[r] = m;
    rinv[r] = 1.f / (ss[0] + ss[1] + ss[2] + ss[3]);
  }
}

// ---------------- K2b (MFMA): ctx_part[blk][bh][d][e] = sum_n p[d][n]*v[e][n] ----------------
__global__ __launch_bounds__(256) void k_context(const u16* __restrict__ qkvb,
    const float* __restrict__ rmax, const float* __restrict__ rinv,
    float* __restrict__ ctxp) {
  int blk = blockIdx.x, bh = blockIdx.y;
  int b = bh >> 2, hd = bh & 3;
  const u16* kb = qkvb + (size_t)b * OC3_ * N_ + (size_t)(HID_ + hd * DH_) * N_;
  const u16* vb = qkvb + (size_t)b * OC3_ * N_ + (size_t)(2 * HID_ + hd * DH_) * N_;
  __shared__ float redl[4096];  // 4 waves x 32x32 fp32 = 16 KiB
  int tid = threadIdx.x;
  int w = tid >> 6, l = tid & 63, l16 = l & 15, quad = l >> 4;
  float rm[2], ri[2];
  #pragma unroll
  for (int mi = 0; mi < 2; mi++) {
    rm[mi] = rmax[bh * 32 + mi * 16 + l16];
    ri[mi] = rinv[bh * 32 + mi * 16 + l16];
  }
  f32x4 acc[2][2] = {};
  int nbase = blk * 1024 + w * 256 + quad * 8;
  #pragma unroll
  for (int kk = 0; kk < 8; kk++) {
    int n0 = nbase + kk * 32;
    short8 af[2], bf[2];
    #pragma unroll
    for (int nj = 0; nj < 2; nj++)
      bf[nj] = *(const short8*)&vb[(size_t)(nj * 16 + l16) * N_ + n0];
    #pragma unroll
    for (int mi = 0; mi < 2; mi++) {
      uint4 u = *(const uint4*)&kb[(size_t)(mi * 16 + l16) * N_ + n0];
      unsigned int uu[4] = {u.x, u.y, u.z, u.w};
      union { unsigned int u[4]; short8 s; } pk;
      #pragma unroll
      for (int j = 0; j < 4; j++) {
        float lo = __expf(b2f((u16)(uu[j] & 0xffff)) - rm[mi]) * ri[mi];
        float hi = __expf(b2f((u16)(uu[j] >> 16))     - rm[mi]) * ri[mi];
        pk.u[j] = cvt_pk(lo, hi);
      }
      af[mi] = pk.s;
    }
    #pragma unroll
    for (int mi = 0; mi < 2; mi++)
      #pragma unroll
      for (int nj = 0; nj < 2; nj++)
        acc[mi][nj] = __builtin_amdgcn_mfma_f32_16x16x32_bf16(af[mi], bf[nj], acc[mi][nj], 0, 0, 0);
  }
  #pragma unroll
  for (int mi = 0; mi < 2; mi++)
    #pragma unroll
    for (int nj = 0; nj < 2; nj++)
      #pragma unroll
      for (int r = 0; r < 4; r++)
        redl[w * 1024 + (mi * 16 + quad * 4 + r) * 32 + nj * 16 + l16] = acc[mi][nj][r];
  __syncthreads();
  float* cp = ctxp + (size_t)blk * 131072 + (size_t)bh * 1024;
  #pragma unroll
  for (int j = 0; j < 4; j++) {
    int idx = j * 256 + tid;
    cp[idx] = redl[idx] + redl[1024 + idx] + redl[2048 + idx] + redl[3072 + idx];
  }
}

// ---------------- K3: q-softmax + hid = ctx^T . q -> hidt[b][n][e] bf16 ----------------
__global__ __launch_bounds__(256) void k_attnout(const u16* __restrict__ qkvb,
    const float* __restrict__ ctxp, u16* __restrict__ hidt) {
  int tile = blockIdx.x, bh = blockIdx.y;
  int b = bh >> 2, hd = bh & 3;
  const u16* qbase = qkvb + (size_t)b * OC3_ * N_ + (size_t)(hd * DH_) * N_;
  __shared__ float cs[32][40];
  __shared__ unsigned int hs[256][16];  // 256 n x 32 bf16 (packed pairs)
  int tid = threadIdx.x;
  for (int idx = tid; idx < 1024; idx += 256) {
    float s = 0.f;
    #pragma unroll
    for (int p = 0; p < CTXP_; p++)
      s += ctxp[(size_t)p * 131072 + (size_t)bh * 1024 + idx];
    int d = idx >> 5, e = idx & 31;
    cs[d][e] = s;
  }
  __syncthreads();
  int n = tile * 256 + tid;
  float q[32];
  float m = -1e30f;
  #pragma unroll
  for (int d = 0; d < 32; d++) { q[d] = b2f(qbase[(size_t)d * N_ + n]); m = fmaxf(m, q[d]); }
  float s = 0.f;
  #pragma unroll
  for (int d = 0; d < 32; d++) { q[d] = __expf(q[d] - m); s += q[d]; }
  float inv = 0.17677669529663687f / s;  // 1/sqrt(32)
  #pragma unroll
  for (int d = 0; d < 32; d++) q[d] *= inv;
  #pragma unroll
  for (int e0 = 0; e0 < 32; e0 += 4) {
    f32x4 a = {};
    #pragma unroll
    for (int d = 0; d < 32; d++) {
      f32x4 c4 = *(const f32x4*)&cs[d][e0];
      a += q[d] * c4;
    }
    hs[tid][e0 / 2 + 0] = cvt_pk(a[0], a[1]);
    hs[tid][e0 / 2 + 1] = cvt_pk(a[2], a[3]);
  }
  __syncthreads();
  #pragma unroll
  for (int it = 0; it < 8; it++) {
    int q2 = it * 256 + tid;          // uint2 chunk: 8 chunks per n-row
    int nl = q2 >> 3, c2 = q2 & 7;
    uint2 v = *(const uint2*)&hs[nl][c2 * 2];
    *(uint2*)&hidt[((size_t)b * N_ + tile * 256 + nl) * HID_ + hd * 32 + c2 * 4] = v;
  }
}

// ---------------- K5: finalize mean/rstd ----------------
__global__ void k_finalize(float* __restrict__ bsum) {
  int b = threadIdx.x;
  if (b < B_) {
    float s1 = bsum[2 * b], s2 = bsum[2 * b + 1];
    float mean = s1 * (1.f / LNM_);
    float var = s2 * (1.f / LNM_) - mean * mean;
    bsum[2 * b] = mean;
    bsum[2 * b + 1] = rsqrtf(var + 1e-5f);
  }
}

// ---------------- K6: normalize + affine in-place ----------------
__global__ __launch_bounds__(256) void k_norm(float* __restrict__ out,
    const float* __restrict__ bsum, const float* __restrict__ gnw,
    const float* __restrict__ gnb) {
  size_t v = (size_t)blockIdx.x * 256 + threadIdx.x;
  int c = (int)((v >> 10) & 255);
  int b = (int)(v >> 18);
  float mean = bsum[2 * b], rstd = bsum[2 * b + 1];
  float w = gnw[c] * rstd;
  float sh = gnb[c] - mean * w;
  float4 x = ((const float4*)out)[v];
  x.x = x.x * w + sh; x.y = x.y * w + sh;
  x.z = x.z * w + sh; x.w = x.w * w + sh;
  ((float4*)out)[v] = x;
}

extern "C" void kernel_launch(void* const* d_in, const int* in_sizes, int n_in,
                              void* d_out, int out_size, void* d_ws, size_t ws_size,
                              hipStream_t stream) {
  const float* x     = (const float*)d_in[0];
  const float* w_qkv = (const float*)d_in[1];
  const float* w_out = (const float*)d_in[2];
  const float* b_out = (const float*)d_in[3];
  const float* gn_w  = (const float*)d_in[4];
  const float* gn_b  = (const float*)d_in[5];
  float* out = (float*)d_out;

  u16* qkvb = (u16*)d_ws;                              // 96 MiB
  u16* hidt = qkvb + (size_t)B_ * OC3_ * N_;           // 32 MiB
  float* ctx  = (float*)(hidt + (size_t)B_ * N_ * HID_);  // 2 MiB (4 partial slabs)
  float* bsum = ctx + CTXP_ * 131072;                  // 64
  float* rmax = bsum + 64;                             // 4096
  float* rinv = rmax + 4096;                           // 4096
  u16* wqb = (u16*)(rinv + 4096);                      // 192 KiB
  u16* wob = wqb + OC3_ * C_;                          // 64 KiB

  k_cast_w<<<384, 256, 0, stream>>>(w_qkv, w_out, wqb, wob, bsum);
  k_gemm_mfma<256, true, true><<<dim3(32, 3, 32), 256, 0, stream>>>(
      wqb, nullptr, x, qkvb, nullptr, nullptr, OC3_);
  k_kstats<<<4096, 256, 0, stream>>>(qkvb, rmax, rinv);
  k_context<<<dim3(CTXP_, 128), 256, 0, stream>>>(qkvb, rmax, rinv, ctx);
  k_attnout<<<dim3(16, 128), 256, 0, stream>>>(qkvb, ctx, hidt);
  k_gemm_mfma<128, false, false><<<dim3(32, 2, 32), 256, 0, stream>>>(
      wob, hidt, nullptr, out, b_out, bsum, C_);
  k_finalize<<<1, 64, 0, stream>>>(bsum);
  k_norm<<<32768, 256, 0, stream>>>(out, bsum, gn_w, gn_b);
}